// Round 15
// baseline (103.895 us; speedup 1.0000x reference)
//
#include <hip/hip_runtime.h>
#include <hip/hip_bf16.h>

typedef float f32x4 __attribute__((ext_vector_type(4)));
typedef __bf16 bf16x8 __attribute__((ext_vector_type(8)));
typedef unsigned short u16;

// Problem dims (fixed): B=128, T=64, H=1024, Hu=512, J=129, N=128, I=64, MJW=64
// ws layout
#define OFF_W1T  0u            // 512x1024 bf16 = 1048576 B  (W1T[n][k] = W1[k][n])
#define OFF_W23B 1048576u      // 144x512 bf16 fragment-order = 147456 B
#define OFF_TS   1196032u      // 8192x512 bf16 = 8388608 B
#define OFF_JWT  9584640u      // 128 x 64(col) x 64(row) f32 = 2097152 B
#define OFF_P0   11681792u     // 8192 f32 = 32768 B

static __device__ __forceinline__ u16 f2bf(float x) {
    __bf16 h = (__bf16)x;
    return __builtin_bit_cast(u16, h);
}

__device__ __forceinline__ void gload16(const void* g, void* l) {
    __builtin_amdgcn_global_load_lds(
        (const __attribute__((address_space(1))) void*)g,
        (__attribute__((address_space(3))) void*)l,
        16, 0, 0);
}

// ---------------------------------------------------------------------------
// prep (unchanged)
// ---------------------------------------------------------------------------
__global__ __launch_bounds__(256) void prep_kernel(
    const float* __restrict__ W1, const float* __restrict__ W2,
    const float* __restrict__ W3,
    __bf16* __restrict__ W1T, __bf16* __restrict__ W23B)
{
    const int t = threadIdx.x;
    if (blockIdx.x < 128) {
        __shared__ __bf16 lds_t[64][72];
        const int kt = blockIdx.x >> 3, nt = blockIdx.x & 7;
        const int k0 = kt * 64, n0 = nt * 64;
        {
            const int kr = t >> 2, c0 = (t & 3) * 16;
            const float* src = W1 + (size_t)(k0 + kr) * 512 + n0 + c0;
            #pragma unroll
            for (int q = 0; q < 4; ++q) {
                float4 v = *(const float4*)(src + q * 4);
                lds_t[kr][c0 + q * 4 + 0] = (__bf16)v.x;
                lds_t[kr][c0 + q * 4 + 1] = (__bf16)v.y;
                lds_t[kr][c0 + q * 4 + 2] = (__bf16)v.z;
                lds_t[kr][c0 + q * 4 + 3] = (__bf16)v.w;
            }
        }
        __syncthreads();
        {
            const int nr = t >> 2, kc = (t & 3) * 16;
            bf16x8 o0, o1;
            #pragma unroll
            for (int j = 0; j < 8; ++j) o0[j] = lds_t[kc + j][nr];
            #pragma unroll
            for (int j = 0; j < 8; ++j) o1[j] = lds_t[kc + 8 + j][nr];
            __bf16* dst = W1T + (size_t)(n0 + nr) * 1024 + k0 + kc;
            *(bf16x8*)(dst)     = o0;
            *(bf16x8*)(dst + 8) = o1;
        }
    } else {
        int g = (blockIdx.x - 128) * 256 + t;   // 0..9215
        if (g < 9216) {
            int n = g >> 6;            // 0..143
            int k8 = (g & 63) * 8;     // 0,8,..,504
            bf16x8 v;
            #pragma unroll
            for (int j = 0; j < 8; ++j) {
                int k = k8 + j;
                float x = 0.0f;
                if (n < 129) x = W2[(size_t)k * 129 + n];
                else if (n == 129) x = W3[k];
                v[j] = (__bf16)x;
            }
            int kk = k8 >> 5, lg = (k8 >> 3) & 3, ct = n >> 4, lr = n & 15;
            *(bf16x8*)&W23B[(((size_t)(kk * 9 + ct)) * 64 + lg * 16 + lr) * 8] = v;
        }
    }
}

// ---------------------------------------------------------------------------
// GEMM1 (adopted from R14 measurement: ring-3, 3 blocks/CU = 12 waves/CU,
// stage-dist-2, vmcnt(4), 1 barrier/step, XCD-chunk swizzle, T21 swizzles).
// Measured ~21-22us standalone vs ~31 for ring-5 2/CU.
// ---------------------------------------------------------------------------
__global__ __launch_bounds__(256, 3) void gemm1_kernel(
    const float* __restrict__ Y, const __bf16* __restrict__ W1T,
    const float* __restrict__ b1, u16* __restrict__ ts)
{
    __shared__ float  As[3][64 * 32];
    __shared__ __bf16 Bs[3][128 * 32];
    const int tid = threadIdx.x;
    const int bid = blockIdx.x;
    const int half = bid >> 8;
    const int b8 = bid & 255;
    const int xcd = b8 & 7;
    const int ii = b8 >> 3;
    const int rb = half * 64 + xcd * 8 + (ii >> 2);
    const int tb = ii & 3;
    const int m0 = rb * 64, n0 = tb * 128;
    const int wid = tid >> 6, lane = tid & 63;
    const int wr = wid >> 1, wc = wid & 1;
    const int lr = lane & 15, lg = lane >> 4;
    const int al = lane >> 3;
    const int au = (lane & 7) ^ al;
    const float* yA0 = Y + (size_t)(m0 + (wid * 2 + 0) * 8 + al) * 1024 + au * 4;
    const float* yA1 = Y + (size_t)(m0 + (wid * 2 + 1) * 8 + al) * 1024 + au * 4;
    const int bl = lane >> 2;
    const int bu = (lane & 3) ^ ((bl >> 1) & 3);
    const __bf16* wB0 = W1T + (size_t)(n0 + (wid * 2 + 0) * 16 + bl) * 1024 + bu * 8;
    const __bf16* wB1 = W1T + (size_t)(n0 + (wid * 2 + 1) * 16 + bl) * 1024 + bu * 8;

    f32x4 acc[2][4];
    #pragma unroll
    for (int m = 0; m < 2; m++)
        #pragma unroll
        for (int n = 0; n < 4; n++) { f32x4 z = {0.f,0.f,0.f,0.f}; acc[m][n] = z; }

#define STAGE(buf, kt) do { \
    gload16(yA0 + (kt) * 32, &As[buf][(wid * 2 + 0) * 256]); \
    gload16(yA1 + (kt) * 32, &As[buf][(wid * 2 + 1) * 256]); \
    gload16(wB0 + (kt) * 32, &Bs[buf][(wid * 2 + 0) * 512]); \
    gload16(wB1 + (kt) * 32, &Bs[buf][(wid * 2 + 1) * 512]); \
} while (0)

#define COMPUTE(buf) do { \
    bf16x8 af[2]; bf16x8 bfr[4]; \
    _Pragma("unroll") \
    for (int m = 0; m < 2; ++m) { \
        const int row = wr * 32 + m * 16 + lr; \
        const int r7 = row & 7; \
        float4 h0 = *(const float4*)&As[buf][row * 32 + (((lg * 2 + 0) ^ r7) * 4)]; \
        float4 h1 = *(const float4*)&As[buf][row * 32 + (((lg * 2 + 1) ^ r7) * 4)]; \
        bf16x8 tt; \
        tt[0]=(__bf16)h0.x; tt[1]=(__bf16)h0.y; tt[2]=(__bf16)h0.z; tt[3]=(__bf16)h0.w; \
        tt[4]=(__bf16)h1.x; tt[5]=(__bf16)h1.y; tt[6]=(__bf16)h1.z; tt[7]=(__bf16)h1.w; \
        af[m] = tt; \
    } \
    _Pragma("unroll") \
    for (int n = 0; n < 4; ++n) { \
        const int rowb = wc * 64 + n * 16 + lr; \
        bfr[n] = *(const bf16x8*)&Bs[buf][rowb * 32 + ((lg ^ ((rowb >> 1) & 3)) * 8)]; \
    } \
    __builtin_amdgcn_s_setprio(1); \
    _Pragma("unroll") \
    for (int m = 0; m < 2; ++m) \
        _Pragma("unroll") \
        for (int n = 0; n < 4; ++n) \
            acc[m][n] = __builtin_amdgcn_mfma_f32_16x16x32_bf16(af[m], bfr[n], acc[m][n], 0, 0, 0); \
    __builtin_amdgcn_s_setprio(0); \
} while (0)

    STAGE(0, 0); STAGE(1, 1);
    {
        int buf = 0, sbuf = 2;
        #pragma unroll 1
        for (int kt = 0; kt < 30; ++kt) {
            asm volatile("s_waitcnt vmcnt(4)" ::: "memory");
            __builtin_amdgcn_s_barrier();
            COMPUTE(buf);
            STAGE(sbuf, kt + 2);
            buf  = (buf  == 2) ? 0 : buf  + 1;
            sbuf = (sbuf == 2) ? 0 : sbuf + 1;
        }
    }
    asm volatile("s_waitcnt vmcnt(4)" ::: "memory");
    __builtin_amdgcn_s_barrier();
    COMPUTE(0);
    asm volatile("s_waitcnt vmcnt(0)" ::: "memory");
    __builtin_amdgcn_s_barrier();
    COMPUTE(1);

    #pragma unroll
    for (int m = 0; m < 2; m++) {
        #pragma unroll
        for (int n = 0; n < 4; n++) {
            int col = n0 + wc * 64 + n * 16 + lr;
            float bias = b1[col];
            #pragma unroll
            for (int j = 0; j < 4; j++) {
                int row = m0 + wr * 32 + m * 16 + lg * 4 + j;
                float v = tanhf(acc[m][n][j] + bias);
                ts[(size_t)row * 512 + col] = f2bf(v);
            }
        }
    }
#undef STAGE
#undef COMPUTE
}

// ---------------------------------------------------------------------------
// band (unchanged)
// ---------------------------------------------------------------------------
__global__ __launch_bounds__(256) void band_kernel(
    const u16* __restrict__ ts, const u16* __restrict__ W23B,
    const float* __restrict__ b2, const float* __restrict__ b3,
    float* __restrict__ jwT, float* __restrict__ p0)
{
    const int b = blockIdx.x;
    const int tid = threadIdx.x;
    const int w = tid >> 6, lane = tid & 63;
    const int lr = lane & 15, lg = lane >> 4;
    const int r0 = b * 64 + w * 16;

    f32x4 acc[9];
    #pragma unroll
    for (int ct = 0; ct < 9; ct++) { f32x4 z = {0.f,0.f,0.f,0.f}; acc[ct] = z; }

    #pragma unroll 4
    for (int kk = 0; kk < 16; ++kk) {
        bf16x8 a = *(const bf16x8*)(ts + (size_t)(r0 + lr) * 512 + kk * 32 + lg * 8);
        #pragma unroll
        for (int ct = 0; ct < 9; ct++) {
            bf16x8 bv = *(const bf16x8*)(W23B + ((size_t)(kk * 9 + ct) * 64 + lane) * 8);
            acc[ct] = __builtin_amdgcn_mfma_f32_16x16x32_bf16(a, bv, acc[ct], 0, 0, 0);
        }
    }

    float b3v = b3[0];
    #pragma unroll
    for (int j = 0; j < 4; j++) {
        int rloc = w * 16 + lg * 4 + j;   // row within batch (0..63)
        float v[9];
        float mx = -1e30f;
        #pragma unroll
        for (int ct = 0; ct < 9; ct++) {
            int col = ct * 16 + lr;
            if (col < 129) { float x = acc[ct][j] + b2[col]; v[ct] = x; mx = fmaxf(mx, x); }
            else v[ct] = -1e30f;
        }
        #pragma unroll
        for (int o = 1; o < 16; o <<= 1) mx = fmaxf(mx, __shfl_xor(mx, o));
        float sum = 0.f;
        #pragma unroll
        for (int ct = 0; ct < 9; ct++) {
            int col = ct * 16 + lr;
            if (col < 129) { float e = expf(v[ct] - mx); v[ct] = e; sum += e; }
        }
        #pragma unroll
        for (int o = 1; o < 16; o <<= 1) sum += __shfl_xor(sum, o);
        float inv = 1.0f / sum;
        #pragma unroll
        for (int ct = 0; ct < 9; ct++) {
            int col = ct * 16 + lr;
            int cc = col - 64 + rloc;
            if (col < 129 && cc >= 0 && cc < 64)
                jwT[((size_t)b * 64 + cc) * 64 + rloc] = v[ct] * inv;
        }
        if (lr == 1) {
            float pv = acc[8][j] + b3v;
            p0[b * 64 + rloc] = 1.0f / (1.0f + expf(-pv));
        }
    }
}

// ---------------------------------------------------------------------------
// recur2: one block = TWO batches, 64 threads (1 wave), 64 blocks.
// A/B clusters issued back-to-back (19 DS ops each incl. next-iter em reads
// -> ZERO compiler memory ops in loop); lgkmcnt(15) = A complete (in-order
// DS) -> FMA(A) overlaps B's latency; lgkmcnt(0) -> FMA(B).
// Per-batch algebra identical to R13 (absmax 0): lazy exponent-flush folded
// into em factors; one butterfly reduce per batch at exit.
// ---------------------------------------------------------------------------
#define CLUSTER(OUT, ut, waddr, rbase, emaddr) \
    asm volatile( \
        "ds_write_b32 %19, %18\n\t" \
        "ds_read_b128 %0, %20 offset:0\n\t" \
        "ds_read_b128 %1, %20 offset:16\n\t" \
        "ds_read_b128 %2, %20 offset:32\n\t" \
        "ds_read_b128 %3, %20 offset:48\n\t" \
        "ds_read_b128 %4, %20 offset:64\n\t" \
        "ds_read_b128 %5, %20 offset:80\n\t" \
        "ds_read_b128 %6, %20 offset:96\n\t" \
        "ds_read_b128 %7, %20 offset:112\n\t" \
        "ds_read_b128 %8, %20 offset:128\n\t" \
        "ds_read_b128 %9, %20 offset:144\n\t" \
        "ds_read_b128 %10, %20 offset:160\n\t" \
        "ds_read_b128 %11, %20 offset:176\n\t" \
        "ds_read_b128 %12, %20 offset:192\n\t" \
        "ds_read_b128 %13, %20 offset:208\n\t" \
        "ds_read_b128 %14, %20 offset:224\n\t" \
        "ds_read_b128 %15, %20 offset:240\n\t" \
        "ds_read_b32 %16, %21\n\t" \
        "ds_read_b32 %17, %21 offset:256" \
        : "=&v"(OUT##0), "=&v"(OUT##1), "=&v"(OUT##2),  "=&v"(OUT##3), \
          "=&v"(OUT##4), "=&v"(OUT##5), "=&v"(OUT##6),  "=&v"(OUT##7), \
          "=&v"(OUT##8), "=&v"(OUT##9), "=&v"(OUT##10), "=&v"(OUT##11), \
          "=&v"(OUT##12),"=&v"(OUT##13),"=&v"(OUT##14), "=&v"(OUT##15), \
          "=&v"(OUT##lo), "=&v"(OUT##hi) \
        : "v"(ut), "v"(waddr), "v"(rbase), "v"(emaddr) \
        : "memory")

__global__ __launch_bounds__(64, 1) void recur2_kernel(
    const float* __restrict__ jwT, const float* __restrict__ p0g,
    const float* __restrict__ em, const int* __restrict__ slen,
    float* __restrict__ out)
{
    __shared__ float emT[2][63][128];   // emT[X][i-1][n] = em[2b+X][n][i], i=1..63
    __shared__ f32x4 a_bc[2][16];
    const int b2 = blockIdx.x, c = threadIdx.x;
    const int bA = 2 * b2, bB = 2 * b2 + 1;

    // bands
    const float* bbA = jwT + ((size_t)bA * 64 + c) * 64;
    const float* bbB = jwT + ((size_t)bB * 64 + c) * 64;
    f32x4 BA0=*(const f32x4*)(bbA+0),  BA1=*(const f32x4*)(bbA+4),  BA2=*(const f32x4*)(bbA+8),  BA3=*(const f32x4*)(bbA+12);
    f32x4 BA4=*(const f32x4*)(bbA+16), BA5=*(const f32x4*)(bbA+20), BA6=*(const f32x4*)(bbA+24), BA7=*(const f32x4*)(bbA+28);
    f32x4 BA8=*(const f32x4*)(bbA+32), BA9=*(const f32x4*)(bbA+36), BA10=*(const f32x4*)(bbA+40),BA11=*(const f32x4*)(bbA+44);
    f32x4 BA12=*(const f32x4*)(bbA+48),BA13=*(const f32x4*)(bbA+52),BA14=*(const f32x4*)(bbA+56),BA15=*(const f32x4*)(bbA+60);
    f32x4 BB0=*(const f32x4*)(bbB+0),  BB1=*(const f32x4*)(bbB+4),  BB2=*(const f32x4*)(bbB+8),  BB3=*(const f32x4*)(bbB+12);
    f32x4 BB4=*(const f32x4*)(bbB+16), BB5=*(const f32x4*)(bbB+20), BB6=*(const f32x4*)(bbB+24), BB7=*(const f32x4*)(bbB+28);
    f32x4 BB8=*(const f32x4*)(bbB+32), BB9=*(const f32x4*)(bbB+36), BB10=*(const f32x4*)(bbB+40),BB11=*(const f32x4*)(bbB+44);
    f32x4 BB12=*(const f32x4*)(bbB+48),BB13=*(const f32x4*)(bbB+52),BB14=*(const f32x4*)(bbB+56),BB15=*(const f32x4*)(bbB+60);

    // stage em transposed (rows 1..63)
    #pragma unroll 1
    for (int X = 0; X < 2; ++X) {
        const float4* eg = (const float4*)(em + (size_t)(bA + X) * 8192);
        #pragma unroll 4
        for (int q = 0; q < 32; ++q) {
            int i4 = c + q * 64;
            float4 v = eg[i4];
            int n = 4 * q + (c >> 4);
            int i0 = (c & 15) * 4;
            #pragma unroll
            for (int j = 0; j < 4; ++j) {
                int r = i0 + j;
                if (r >= 1 && r < 64) emT[X][r - 1][n] = (&v.x)[j];
            }
        }
    }
    const float p0A = p0g[bA * 64 + c], p0B = p0g[bB * 64 + c];
    const int idxA = slen[bA] - 1, idxB = slen[bB] - 1;
    const int maxidx = idxA > idxB ? idxA : idxB;
    __syncthreads();

    // init (em row 0 direct from global; one-time)
    float utA = em[(size_t)bA * 8192 + c * 64] + em[(size_t)bA * 8192 + (c + 64) * 64];
    float utB = em[(size_t)bB * 8192 + c * 64] + em[(size_t)bB * 8192 + (c + 64) * 64];
    int EaccA = 0, EaccB = 0;

    unsigned rbaseA = (unsigned)(uintptr_t)(__attribute__((address_space(3))) void*)&a_bc[0][0];
    unsigned rbaseB = (unsigned)(uintptr_t)(__attribute__((address_space(3))) void*)&a_bc[1][0];
    unsigned waA = rbaseA + (unsigned)c * 4u;
    unsigned waB = rbaseB + (unsigned)c * 4u;
    unsigned embA = (unsigned)(uintptr_t)(__attribute__((address_space(3))) void*)&emT[0][0][0];
    unsigned embB = (unsigned)(uintptr_t)(__attribute__((address_space(3))) void*)&emT[1][0][0];

    float emloA = emT[0][0][c], emhiA = emT[0][0][c + 64];   // row i=1
    float emloB = emT[1][0][c], emhiB = emT[1][0][c + 64];

    #pragma unroll 1
    for (int i = 1; i <= maxidx; ++i) {
        int ei = (i <= 62) ? i : 0;                 // next-iter row (i+1) at idx i
        unsigned eaA = embA + (unsigned)(ei * 512 + c * 4);
        unsigned eaB = embB + (unsigned)(ei * 512 + c * 4);
        f32x4 A0,A1,A2,A3,A4,A5,A6,A7,A8,A9,A10,A11,A12,A13,A14,A15; float Alo, Ahi;
        CLUSTER(A, utA, waA, rbaseA, eaA);
        int bitsA = __builtin_amdgcn_readfirstlane(__float_as_int(utA));
        int efA = (bitsA >> 23) & 255;
        EaccA += (i <= idxA) ? (efA - 127) : 0;
        float scaleA = __int_as_float((254 - efA) << 23);
        float eAlo = emloA * scaleA, eAhi = emhiA * p0A * scaleA;
        f32x4 C0,C1,C2,C3,C4,C5,C6,C7,C8,C9,C10,C11,C12,C13,C14,C15; float Clo, Chi;
        CLUSTER(C, utB, waB, rbaseB, eaB);
        int bitsB = __builtin_amdgcn_readfirstlane(__float_as_int(utB));
        int efB = (bitsB >> 23) & 255;
        EaccB += (i <= idxB) ? (efB - 127) : 0;
        float scaleB = __int_as_float((254 - efB) << 23);
        float eBlo = emloB * scaleB, eBhi = emhiB * p0B * scaleB;

        asm volatile("s_waitcnt lgkmcnt(15)" ::: "memory");   // A's 19 ops done (in-order)
        __builtin_amdgcn_sched_barrier(0);
        {
            f32x4 va = A0 * BA0,  vb = A1 * BA1,  vc = A2 * BA2,  vd = A3 * BA3;
            va = va + A4 * BA4;   vb = vb + A5 * BA5;   vc = vc + A6 * BA6;   vd = vd + A7 * BA7;
            va = va + A8 * BA8;   vb = vb + A9 * BA9;   vc = vc + A10 * BA10; vd = vd + A11 * BA11;
            va = va + A12 * BA12; vb = vb + A13 * BA13; vc = vc + A14 * BA14; vd = vd + A15 * BA15;
            f32x4 vs = (va + vb) + (vc + vd);
            float sum = (vs[0] + vs[1]) + (vs[2] + vs[3]);
            float nut = sum * eAlo + utA * eAhi;
            utA = (i <= idxA) ? nut : utA;
        }
        asm volatile("s_waitcnt lgkmcnt(0)" ::: "memory");    // B's ops done
        __builtin_amdgcn_sched_barrier(0);
        {
            f32x4 va = C0 * BB0,  vb = C1 * BB1,  vc = C2 * BB2,  vd = C3 * BB3;
            va = va + C4 * BB4;   vb = vb + C5 * BB5;   vc = vc + C6 * BB6;   vd = vd + C7 * BB7;
            va = va + C8 * BB8;   vb = vb + C9 * BB9;   vc = vc + C10 * BB10; vd = vd + C11 * BB11;
            va = va + C12 * BB12; vb = vb + C13 * BB13; vc = vc + C14 * BB14; vd = vd + C15 * BB15;
            f32x4 vs = (va + vb) + (vc + vd);
            float sum = (vs[0] + vs[1]) + (vs[2] + vs[3]);
            float nut = sum * eBlo + utB * eBhi;
            utB = (i <= idxB) ? nut : utB;
        }
        // next-iter em came out of the clusters (already waited)
        emloA = Alo; emhiA = Ahi;
        emloB = Clo; emhiB = Chi;
    }

    float rA = utA;
    #pragma unroll
    for (int o = 1; o < 64; o <<= 1) rA += __shfl_xor(rA, o);
    float rB = utB;
    #pragma unroll
    for (int o = 1; o < 64; o <<= 1) rB += __shfl_xor(rB, o);
    if (c == 0) {
        out[bA] = (idxA > 0)
            ? 1.0f + 0.6931471805599453f * ((float)EaccA + __log2f(rA) + 7.0f * (float)idxA)
            : 1.0f;
        out[bB] = (idxB > 0)
            ? 1.0f + 0.6931471805599453f * ((float)EaccB + __log2f(rB) + 7.0f * (float)idxB)
            : 1.0f;
    }
}
#undef CLUSTER

extern "C" void kernel_launch(void* const* d_in, const int* in_sizes, int n_in,
                              void* d_out, int out_size, void* d_ws, size_t ws_size,
                              hipStream_t stream)
{
    const float* Y   = (const float*)d_in[0];
    const float* em  = (const float*)d_in[1];
    const int*   sl  = (const int*)d_in[2];
    const float* W1  = (const float*)d_in[3];
    const float* b1  = (const float*)d_in[4];
    const float* W2  = (const float*)d_in[5];
    const float* b2  = (const float*)d_in[6];
    const float* W3  = (const float*)d_in[7];
    const float* b3  = (const float*)d_in[8];
    float* out = (float*)d_out;
    char* ws = (char*)d_ws;

    __bf16* W1T  = (__bf16*)(ws + OFF_W1T);
    __bf16* W23B = (__bf16*)(ws + OFF_W23B);
    u16*    ts   = (u16*)(ws + OFF_TS);
    float*  jwT  = (float*)(ws + OFF_JWT);
    float*  p0   = (float*)(ws + OFF_P0);

    prep_kernel<<<164, 256, 0, stream>>>(W1, W2, W3, W1T, W23B);
    gemm1_kernel<<<512, 256, 0, stream>>>(Y, W1T, b1, ts);
    band_kernel<<<128, 256, 0, stream>>>(ts, (const u16*)W23B, b2, b3, jwT, p0);
    recur2_kernel<<<64, 64, 0, stream>>>(jwT, p0, em, sl, out);
}

// Round 16
// 76.169 us; speedup vs baseline: 1.3640x; 1.3640x over previous
//
#include <hip/hip_runtime.h>
#include <hip/hip_bf16.h>

typedef float f32x4 __attribute__((ext_vector_type(4)));
typedef __bf16 bf16x8 __attribute__((ext_vector_type(8)));
typedef unsigned short u16;

// Problem dims (fixed): B=128, T=64, H=1024, Hu=512, J=129, N=128, I=64, MJW=64
// ws layout
#define OFF_W1T  0u            // 512x1024 bf16 = 1048576 B  (W1T[n][k] = W1[k][n])
#define OFF_W23B 1048576u      // 144x512 bf16 fragment-order = 147456 B
#define OFF_TS   1196032u      // 8192x512 bf16 = 8388608 B
#define OFF_JWT  9584640u      // 128 x 64(col) x 64(row) f32 = 2097152 B
#define OFF_P0   11681792u     // 8192 f32 = 32768 B

static __device__ __forceinline__ u16 f2bf(float x) {
    __bf16 h = (__bf16)x;
    return __builtin_bit_cast(u16, h);
}

__device__ __forceinline__ void gload16(const void* g, void* l) {
    __builtin_amdgcn_global_load_lds(
        (const __attribute__((address_space(1))) void*)g,
        (__attribute__((address_space(3))) void*)l,
        16, 0, 0);
}

// ---------------------------------------------------------------------------
// prep (unchanged)
// ---------------------------------------------------------------------------
__global__ __launch_bounds__(256) void prep_kernel(
    const float* __restrict__ W1, const float* __restrict__ W2,
    const float* __restrict__ W3,
    __bf16* __restrict__ W1T, __bf16* __restrict__ W23B)
{
    const int t = threadIdx.x;
    if (blockIdx.x < 128) {
        __shared__ __bf16 lds_t[64][72];
        const int kt = blockIdx.x >> 3, nt = blockIdx.x & 7;
        const int k0 = kt * 64, n0 = nt * 64;
        {
            const int kr = t >> 2, c0 = (t & 3) * 16;
            const float* src = W1 + (size_t)(k0 + kr) * 512 + n0 + c0;
            #pragma unroll
            for (int q = 0; q < 4; ++q) {
                float4 v = *(const float4*)(src + q * 4);
                lds_t[kr][c0 + q * 4 + 0] = (__bf16)v.x;
                lds_t[kr][c0 + q * 4 + 1] = (__bf16)v.y;
                lds_t[kr][c0 + q * 4 + 2] = (__bf16)v.z;
                lds_t[kr][c0 + q * 4 + 3] = (__bf16)v.w;
            }
        }
        __syncthreads();
        {
            const int nr = t >> 2, kc = (t & 3) * 16;
            bf16x8 o0, o1;
            #pragma unroll
            for (int j = 0; j < 8; ++j) o0[j] = lds_t[kc + j][nr];
            #pragma unroll
            for (int j = 0; j < 8; ++j) o1[j] = lds_t[kc + 8 + j][nr];
            __bf16* dst = W1T + (size_t)(n0 + nr) * 1024 + k0 + kc;
            *(bf16x8*)(dst)     = o0;
            *(bf16x8*)(dst + 8) = o1;
        }
    } else {
        int g = (blockIdx.x - 128) * 256 + t;   // 0..9215
        if (g < 9216) {
            int n = g >> 6;            // 0..143
            int k8 = (g & 63) * 8;     // 0,8,..,504
            bf16x8 v;
            #pragma unroll
            for (int j = 0; j < 8; ++j) {
                int k = k8 + j;
                float x = 0.0f;
                if (n < 129) x = W2[(size_t)k * 129 + n];
                else if (n == 129) x = W3[k];
                v[j] = (__bf16)x;
            }
            int kk = k8 >> 5, lg = (k8 >> 3) & 3, ct = n >> 4, lr = n & 15;
            *(bf16x8*)&W23B[(((size_t)(kk * 9 + ct)) * 64 + lg * 16 + lr) * 8] = v;
        }
    }
}

// ---------------------------------------------------------------------------
// GEMM1: ring-3, 3 blocks/CU (12 waves/CU), stage-dist-2, vmcnt(4),
// 1 barrier/step, XCD-chunk swizzle, T21 both-sides swizzles.
// R14-measured ~22us standalone.
// ---------------------------------------------------------------------------
__global__ __launch_bounds__(256, 3) void gemm1_kernel(
    const float* __restrict__ Y, const __bf16* __restrict__ W1T,
    const float* __restrict__ b1, u16* __restrict__ ts)
{
    __shared__ float  As[3][64 * 32];
    __shared__ __bf16 Bs[3][128 * 32];
    const int tid = threadIdx.x;
    const int bid = blockIdx.x;
    const int half = bid >> 8;
    const int b8 = bid & 255;
    const int xcd = b8 & 7;
    const int ii = b8 >> 3;
    const int rb = half * 64 + xcd * 8 + (ii >> 2);
    const int tb = ii & 3;
    const int m0 = rb * 64, n0 = tb * 128;
    const int wid = tid >> 6, lane = tid & 63;
    const int wr = wid >> 1, wc = wid & 1;
    const int lr = lane & 15, lg = lane >> 4;
    const int al = lane >> 3;
    const int au = (lane & 7) ^ al;
    const float* yA0 = Y + (size_t)(m0 + (wid * 2 + 0) * 8 + al) * 1024 + au * 4;
    const float* yA1 = Y + (size_t)(m0 + (wid * 2 + 1) * 8 + al) * 1024 + au * 4;
    const int bl = lane >> 2;
    const int bu = (lane & 3) ^ ((bl >> 1) & 3);
    const __bf16* wB0 = W1T + (size_t)(n0 + (wid * 2 + 0) * 16 + bl) * 1024 + bu * 8;
    const __bf16* wB1 = W1T + (size_t)(n0 + (wid * 2 + 1) * 16 + bl) * 1024 + bu * 8;

    f32x4 acc[2][4];
    #pragma unroll
    for (int m = 0; m < 2; m++)
        #pragma unroll
        for (int n = 0; n < 4; n++) { f32x4 z = {0.f,0.f,0.f,0.f}; acc[m][n] = z; }

#define STAGE(buf, kt) do { \
    gload16(yA0 + (kt) * 32, &As[buf][(wid * 2 + 0) * 256]); \
    gload16(yA1 + (kt) * 32, &As[buf][(wid * 2 + 1) * 256]); \
    gload16(wB0 + (kt) * 32, &Bs[buf][(wid * 2 + 0) * 512]); \
    gload16(wB1 + (kt) * 32, &Bs[buf][(wid * 2 + 1) * 512]); \
} while (0)

#define COMPUTE(buf) do { \
    bf16x8 af[2]; bf16x8 bfr[4]; \
    _Pragma("unroll") \
    for (int m = 0; m < 2; ++m) { \
        const int row = wr * 32 + m * 16 + lr; \
        const int r7 = row & 7; \
        float4 h0 = *(const float4*)&As[buf][row * 32 + (((lg * 2 + 0) ^ r7) * 4)]; \
        float4 h1 = *(const float4*)&As[buf][row * 32 + (((lg * 2 + 1) ^ r7) * 4)]; \
        bf16x8 tt; \
        tt[0]=(__bf16)h0.x; tt[1]=(__bf16)h0.y; tt[2]=(__bf16)h0.z; tt[3]=(__bf16)h0.w; \
        tt[4]=(__bf16)h1.x; tt[5]=(__bf16)h1.y; tt[6]=(__bf16)h1.z; tt[7]=(__bf16)h1.w; \
        af[m] = tt; \
    } \
    _Pragma("unroll") \
    for (int n = 0; n < 4; ++n) { \
        const int rowb = wc * 64 + n * 16 + lr; \
        bfr[n] = *(const bf16x8*)&Bs[buf][rowb * 32 + ((lg ^ ((rowb >> 1) & 3)) * 8)]; \
    } \
    __builtin_amdgcn_s_setprio(1); \
    _Pragma("unroll") \
    for (int m = 0; m < 2; ++m) \
        _Pragma("unroll") \
        for (int n = 0; n < 4; ++n) \
            acc[m][n] = __builtin_amdgcn_mfma_f32_16x16x32_bf16(af[m], bfr[n], acc[m][n], 0, 0, 0); \
    __builtin_amdgcn_s_setprio(0); \
} while (0)

    STAGE(0, 0); STAGE(1, 1);
    {
        int buf = 0, sbuf = 2;
        #pragma unroll 1
        for (int kt = 0; kt < 30; ++kt) {
            asm volatile("s_waitcnt vmcnt(4)" ::: "memory");
            __builtin_amdgcn_s_barrier();
            COMPUTE(buf);
            STAGE(sbuf, kt + 2);
            buf  = (buf  == 2) ? 0 : buf  + 1;
            sbuf = (sbuf == 2) ? 0 : sbuf + 1;
        }
    }
    asm volatile("s_waitcnt vmcnt(4)" ::: "memory");
    __builtin_amdgcn_s_barrier();
    COMPUTE(0);
    asm volatile("s_waitcnt vmcnt(0)" ::: "memory");
    __builtin_amdgcn_s_barrier();
    COMPUTE(1);

    #pragma unroll
    for (int m = 0; m < 2; m++) {
        #pragma unroll
        for (int n = 0; n < 4; n++) {
            int col = n0 + wc * 64 + n * 16 + lr;
            float bias = b1[col];
            #pragma unroll
            for (int j = 0; j < 4; j++) {
                int row = m0 + wr * 32 + m * 16 + lg * 4 + j;
                float v = tanhf(acc[m][n][j] + bias);
                ts[(size_t)row * 512 + col] = f2bf(v);
            }
        }
    }
#undef STAGE
#undef COMPUTE
}

// ---------------------------------------------------------------------------
// band (unchanged)
// ---------------------------------------------------------------------------
__global__ __launch_bounds__(256) void band_kernel(
    const u16* __restrict__ ts, const u16* __restrict__ W23B,
    const float* __restrict__ b2, const float* __restrict__ b3,
    float* __restrict__ jwT, float* __restrict__ p0)
{
    const int b = blockIdx.x;
    const int tid = threadIdx.x;
    const int w = tid >> 6, lane = tid & 63;
    const int lr = lane & 15, lg = lane >> 4;
    const int r0 = b * 64 + w * 16;

    f32x4 acc[9];
    #pragma unroll
    for (int ct = 0; ct < 9; ct++) { f32x4 z = {0.f,0.f,0.f,0.f}; acc[ct] = z; }

    #pragma unroll 4
    for (int kk = 0; kk < 16; ++kk) {
        bf16x8 a = *(const bf16x8*)(ts + (size_t)(r0 + lr) * 512 + kk * 32 + lg * 8);
        #pragma unroll
        for (int ct = 0; ct < 9; ct++) {
            bf16x8 bv = *(const bf16x8*)(W23B + ((size_t)(kk * 9 + ct) * 64 + lane) * 8);
            acc[ct] = __builtin_amdgcn_mfma_f32_16x16x32_bf16(a, bv, acc[ct], 0, 0, 0);
        }
    }

    float b3v = b3[0];
    #pragma unroll
    for (int j = 0; j < 4; j++) {
        int rloc = w * 16 + lg * 4 + j;   // row within batch (0..63)
        float v[9];
        float mx = -1e30f;
        #pragma unroll
        for (int ct = 0; ct < 9; ct++) {
            int col = ct * 16 + lr;
            if (col < 129) { float x = acc[ct][j] + b2[col]; v[ct] = x; mx = fmaxf(mx, x); }
            else v[ct] = -1e30f;
        }
        #pragma unroll
        for (int o = 1; o < 16; o <<= 1) mx = fmaxf(mx, __shfl_xor(mx, o));
        float sum = 0.f;
        #pragma unroll
        for (int ct = 0; ct < 9; ct++) {
            int col = ct * 16 + lr;
            if (col < 129) { float e = expf(v[ct] - mx); v[ct] = e; sum += e; }
        }
        #pragma unroll
        for (int o = 1; o < 16; o <<= 1) sum += __shfl_xor(sum, o);
        float inv = 1.0f / sum;
        #pragma unroll
        for (int ct = 0; ct < 9; ct++) {
            int col = ct * 16 + lr;
            int cc = col - 64 + rloc;
            if (col < 129 && cc >= 0 && cc < 64)
                jwT[((size_t)b * 64 + cc) * 64 + rloc] = v[ct] * inv;
        }
        if (lr == 1) {
            float pv = acc[8][j] + b3v;
            p0[b * 64 + rloc] = 1.0f / (1.0f + expf(-pv));
        }
    }
}

// ---------------------------------------------------------------------------
// recur (R13 structure, one block = one batch, 64 threads): the two per-iter
// em prefetch reads moved INSIDE the asm cluster (per-lane addr; em_s[128][65]
// layout -> bank (c+i)%32, conflict-free) so the loop body has zero
// compiler-emitted DS ops; one lgkmcnt(0) covers exactly the cluster.
// Lazy exponent-flush folded into em factors (proven absmax 0).
// ---------------------------------------------------------------------------
__global__ __launch_bounds__(64, 1) void recur_kernel(
    const float* __restrict__ jwT, const float* __restrict__ p0g,
    const float* __restrict__ em, const int* __restrict__ slen,
    float* __restrict__ out)
{
    __shared__ float em_s[128][65];
    __shared__ f32x4 a_bc4[16];
    const int b = blockIdx.x, c = threadIdx.x;

    const float* bb = jwT + ((size_t)b * 64 + c) * 64;
    f32x4 B0  = *(const f32x4*)(bb + 0);
    f32x4 B1  = *(const f32x4*)(bb + 4);
    f32x4 B2  = *(const f32x4*)(bb + 8);
    f32x4 B3  = *(const f32x4*)(bb + 12);
    f32x4 B4  = *(const f32x4*)(bb + 16);
    f32x4 B5  = *(const f32x4*)(bb + 20);
    f32x4 B6  = *(const f32x4*)(bb + 24);
    f32x4 B7  = *(const f32x4*)(bb + 28);
    f32x4 B8  = *(const f32x4*)(bb + 32);
    f32x4 B9  = *(const f32x4*)(bb + 36);
    f32x4 B10 = *(const f32x4*)(bb + 40);
    f32x4 B11 = *(const f32x4*)(bb + 44);
    f32x4 B12 = *(const f32x4*)(bb + 48);
    f32x4 B13 = *(const f32x4*)(bb + 52);
    f32x4 B14 = *(const f32x4*)(bb + 56);
    f32x4 B15 = *(const f32x4*)(bb + 60);

    {
        const float4* eg = (const float4*)(em + (size_t)b * 8192);
        #pragma unroll 8
        for (int q = 0; q < 32; ++q) {
            int i4 = c + q * 64;
            float4 v = eg[i4];
            int base = i4 * 4; int n = base >> 6; int ii = base & 63;
            em_s[n][ii] = v.x; em_s[n][ii + 1] = v.y; em_s[n][ii + 2] = v.z; em_s[n][ii + 3] = v.w;
        }
    }
    const float p0r = p0g[b * 64 + c];
    const int idx = slen[b] - 1;
    __syncthreads();

    float ut = em_s[c][0] + em_s[c + 64][0];   // raw state
    int Eacc = 0;

    unsigned rbase = (unsigned)(uintptr_t)(__attribute__((address_space(3))) void*)&a_bc4[0];
    unsigned waddr = rbase + (unsigned)c * 4u;
    // em_s row base byte addrs for this lane (row c and row c+64)
    unsigned emlo_base = (unsigned)(uintptr_t)(__attribute__((address_space(3))) void*)&em_s[c][0];
    unsigned emhi_base = (unsigned)(uintptr_t)(__attribute__((address_space(3))) void*)&em_s[c + 64][0];

    float em_lo = em_s[c][1];       // prefetched for i=1
    float em_hi = em_s[c + 64][1];

    #pragma unroll 1
    for (int i = 1; i <= idx; ++i) {
        // per-lane addresses of em_s[c][i+1] / em_s[c+64][i+1] (pad col 64 safe)
        unsigned ealo = emlo_base + (unsigned)((i + 1) * 4);
        unsigned eahi = emhi_base + (unsigned)((i + 1) * 4);
        f32x4 A0,A1,A2,A3,A4,A5,A6,A7,A8,A9,A10,A11,A12,A13,A14,A15;
        float nlo, nhi;
        asm volatile(
            "ds_write_b32 %19, %18\n\t"
            "ds_read_b128 %0, %20 offset:0\n\t"
            "ds_read_b128 %1, %20 offset:16\n\t"
            "ds_read_b128 %2, %20 offset:32\n\t"
            "ds_read_b128 %3, %20 offset:48\n\t"
            "ds_read_b128 %4, %20 offset:64\n\t"
            "ds_read_b128 %5, %20 offset:80\n\t"
            "ds_read_b128 %6, %20 offset:96\n\t"
            "ds_read_b128 %7, %20 offset:112\n\t"
            "ds_read_b128 %8, %20 offset:128\n\t"
            "ds_read_b128 %9, %20 offset:144\n\t"
            "ds_read_b128 %10, %20 offset:160\n\t"
            "ds_read_b128 %11, %20 offset:176\n\t"
            "ds_read_b128 %12, %20 offset:192\n\t"
            "ds_read_b128 %13, %20 offset:208\n\t"
            "ds_read_b128 %14, %20 offset:224\n\t"
            "ds_read_b128 %15, %20 offset:240\n\t"
            "ds_read_b32 %16, %21\n\t"
            "ds_read_b32 %17, %22"
            : "=&v"(A0), "=&v"(A1), "=&v"(A2),  "=&v"(A3),
              "=&v"(A4), "=&v"(A5), "=&v"(A6),  "=&v"(A7),
              "=&v"(A8), "=&v"(A9), "=&v"(A10), "=&v"(A11),
              "=&v"(A12),"=&v"(A13),"=&v"(A14), "=&v"(A15),
              "=&v"(nlo), "=&v"(nhi)
            : "v"(ut), "v"(waddr), "v"(rbase), "v"(ealo), "v"(eahi)
            : "memory");
        // flush overlaps the DS latency; scale folded into this iter's em
        int bits = __builtin_amdgcn_readfirstlane(__float_as_int(ut));
        int ef = (bits >> 23) & 255;
        Eacc += ef - 127;
        float scale = __int_as_float((254 - ef) << 23);
        float emlo_eff = em_lo * scale;
        float emhi_eff = em_hi * p0r * scale;
        asm volatile("s_waitcnt lgkmcnt(0)" ::: "memory");
        __builtin_amdgcn_sched_barrier(0);
        f32x4 va = A0 * B0;
        f32x4 vb = A1 * B1;
        f32x4 vc = A2 * B2;
        f32x4 vd = A3 * B3;
        va = va + A4 * B4;   vb = vb + A5 * B5;
        vc = vc + A6 * B6;   vd = vd + A7 * B7;
        va = va + A8 * B8;   vb = vb + A9 * B9;
        vc = vc + A10 * B10; vd = vd + A11 * B11;
        va = va + A12 * B12; vb = vb + A13 * B13;
        vc = vc + A14 * B14; vd = vd + A15 * B15;
        f32x4 vs = (va + vb) + (vc + vd);
        float sum = (vs[0] + vs[1]) + (vs[2] + vs[3]);
        ut = sum * emlo_eff + ut * emhi_eff;
        em_lo = nlo; em_hi = nhi;
    }
    float r = ut;
    #pragma unroll
    for (int o = 1; o < 64; o <<= 1) r += __shfl_xor(r, o);
    if (c == 0) {
        float res = 1.0f;
        if (idx > 0)
            res = 1.0f + 0.6931471805599453f * ((float)Eacc + __log2f(r) + 7.0f * (float)idx);
        out[b] = res;
    }
}

extern "C" void kernel_launch(void* const* d_in, const int* in_sizes, int n_in,
                              void* d_out, int out_size, void* d_ws, size_t ws_size,
                              hipStream_t stream)
{
    const float* Y   = (const float*)d_in[0];
    const float* em  = (const float*)d_in[1];
    const int*   sl  = (const int*)d_in[2];
    const float* W1  = (const float*)d_in[3];
    const float* b1  = (const float*)d_in[4];
    const float* W2  = (const float*)d_in[5];
    const float* b2  = (const float*)d_in[6];
    const float* W3  = (const float*)d_in[7];
    const float* b3  = (const float*)d_in[8];
    float* out = (float*)d_out;
    char* ws = (char*)d_ws;

    __bf16* W1T  = (__bf16*)(ws + OFF_W1T);
    __bf16* W23B = (__bf16*)(ws + OFF_W23B);
    u16*    ts   = (u16*)(ws + OFF_TS);
    float*  jwT  = (float*)(ws + OFF_JWT);
    float*  p0   = (float*)(ws + OFF_P0);

    prep_kernel<<<164, 256, 0, stream>>>(W1, W2, W3, W1T, W23B);
    gemm1_kernel<<<512, 256, 0, stream>>>(Y, W1T, b1, ts);
    band_kernel<<<128, 256, 0, stream>>>(ts, (const u16*)W23B, b2, b3, jwT, p0);
    recur_kernel<<<128, 64, 0, stream>>>(jwT, p0, em, sl, out);
}